// Round 4
// baseline (3158.874 us; speedup 1.0000x reference)
//
#include <hip/hip_runtime.h>

#define DIM 2048
#define LEAK 0.2f

typedef __bf16 bf16x8 __attribute__((ext_vector_type(8)));
typedef float  f32x4  __attribute__((ext_vector_type(4)));
typedef unsigned int u32x4 __attribute__((ext_vector_type(4)));
typedef int    i32x4  __attribute__((ext_vector_type(4)));

static __device__ __forceinline__ unsigned short f2bf(float f) {
    unsigned int x = __float_as_uint(f);
    return (unsigned short)((x + 0x7fffu + ((x >> 16) & 1u)) >> 16);  // RNE
}
static __device__ __forceinline__ float bf2f(unsigned short h) {
    return __uint_as_float(((unsigned int)h) << 16);
}

static __device__ __forceinline__ void async16(const void* g, void* s) {
    __builtin_amdgcn_global_load_lds(
        (const __attribute__((address_space(1))) void*)g,
        (__attribute__((address_space(3))) void*)s, 16, 0, 0);
}

static __device__ __forceinline__ bf16x8 ld_bf16_frag(const char* p) {
    union { u32x4 u; bf16x8 v; } cv;
    cv.u = *(const u32x4*)p;   // ds_read_b128
    return cv.v;
}

// ---------------- prep kernels ----------------

__global__ __launch_bounds__(256) void split_kernel(
    const float* __restrict__ in,
    unsigned short* __restrict__ hi, unsigned short* __restrict__ lo) {
    int idx = blockIdx.x * 256 + threadIdx.x;
    float4 v = ((const float4*)in)[idx];
    ushort4 h, l;
    h.x = f2bf(v.x); l.x = f2bf(v.x - bf2f(h.x));
    h.y = f2bf(v.y); l.y = f2bf(v.y - bf2f(h.y));
    h.z = f2bf(v.z); l.z = f2bf(v.z - bf2f(h.z));
    h.w = f2bf(v.w); l.w = f2bf(v.w - bf2f(h.w));
    ((ushort4*)hi)[idx] = h;
    ((ushort4*)lo)[idx] = l;
}

__global__ __launch_bounds__(256) void transpose_split(
    const float* __restrict__ in,
    unsigned short* __restrict__ hiT, unsigned short* __restrict__ loT) {
    __shared__ float t[32][33];
    int bx = blockIdx.x, by = blockIdx.y;
    int tx = threadIdx.x & 31, ty4 = (threadIdx.x >> 5) << 2;
#pragma unroll
    for (int i = 0; i < 4; i++)
        t[ty4 + i][tx] = in[(size_t)(by * 32 + ty4 + i) * DIM + bx * 32 + tx];
    __syncthreads();
#pragma unroll
    for (int i = 0; i < 4; i++) {
        float v = t[tx][ty4 + i];
        size_t o = (size_t)(bx * 32 + ty4 + i) * DIM + by * 32 + tx;
        unsigned short h = f2bf(v);
        hiT[o] = h;
        loT[o] = f2bf(v - bf2f(h));
    }
}

__global__ __launch_bounds__(256) void transpose_i8(
    const float* __restrict__ in, signed char* __restrict__ outT) {
    __shared__ float t[32][33];
    int bx = blockIdx.x, by = blockIdx.y;
    int tx = threadIdx.x & 31, ty4 = (threadIdx.x >> 5) << 2;
#pragma unroll
    for (int i = 0; i < 4; i++)
        t[ty4 + i][tx] = in[(size_t)(by * 32 + ty4 + i) * DIM + bx * 32 + tx];
    __syncthreads();
#pragma unroll
    for (int i = 0; i < 4; i++)
        outT[(size_t)(bx * 32 + ty4 + i) * DIM + by * 32 + tx] =
            (signed char)t[tx][ty4 + i];
}

__global__ __launch_bounds__(256) void quant_split(
    const float* __restrict__ in,
    signed char* __restrict__ hi, signed char* __restrict__ lo) {
    int idx = blockIdx.x * 256 + threadIdx.x;
    float4 v = ((const float4*)in)[idx];
    char4 h, l;
    {
        int q = (int)rintf(v.x * 16384.f); q = q > 16383 ? 16383 : (q < -16383 ? -16383 : q);
        h.x = (signed char)(q >> 7); l.x = (signed char)(q & 127);
    }
    {
        int q = (int)rintf(v.y * 16384.f); q = q > 16383 ? 16383 : (q < -16383 ? -16383 : q);
        h.y = (signed char)(q >> 7); l.y = (signed char)(q & 127);
    }
    {
        int q = (int)rintf(v.z * 16384.f); q = q > 16383 ? 16383 : (q < -16383 ? -16383 : q);
        h.z = (signed char)(q >> 7); l.z = (signed char)(q & 127);
    }
    {
        int q = (int)rintf(v.w * 16384.f); q = q > 16383 ? 16383 : (q < -16383 ? -16383 : q);
        h.w = (signed char)(q >> 7); l.w = (signed char)(q & 127);
    }
    ((char4*)hi)[idx] = h;
    ((char4*)lo)[idx] = l;
}

// ---------------- bf16 dual-A GEMM (drive), tile 64x128, dbuf ----------------
// MODE 0: Cout = (Ahi+Alo) @ B^T        MODE 1: Cout = Cin + P + bias[n]
// (unchanged from the proven round-0 kernel)
template <int MODE>
__global__ __launch_bounds__(256) void gemm_bf16(
    const unsigned short* __restrict__ Ahi,
    const unsigned short* __restrict__ Alo,
    const unsigned short* __restrict__ BT,
    const float* __restrict__ Cin,
    const float* __restrict__ bias,
    float* __restrict__ Cout) {
    __shared__ alignas(16) char sA[2][16384];
    __shared__ alignas(16) char sB[2][16384];

    const int bid = blockIdx.x;
    const int xcd = bid & 7, slot = bid >> 3;
    const int tm = ((xcd >> 1) << 3) + (slot >> 3);      // 0..31
    const int tn = ((xcd & 1) << 3) + (slot & 7);        // 0..15
    const int row0 = tm << 6, col0 = tn << 7;

    const int tid = threadIdx.x;
    const int lane = tid & 63;
    const int quad = lane >> 4, l16 = lane & 15;
    const int wave = tid >> 6;
    const int wm = wave >> 1, wn = wave & 1;

    const unsigned short* a_src[4]; int a_dst[4];
    const unsigned short* b_src[4]; int b_dst[4];
#pragma unroll
    for (int i = 0; i < 4; i++) {
        int s = tid + 256 * i;                 // 0..1023
        {
            int r = s >> 4, g = (s >> 3) & 1, c = (s & 7) ^ (r & 7);
            a_src[i] = (g ? Alo : Ahi) + (size_t)(row0 + r) * DIM + c * 8;
            a_dst[i] = s * 16;
        }
        {
            int r = s >> 3, c = (s & 7) ^ (r & 7);
            b_src[i] = BT + (size_t)(col0 + r) * DIM + c * 8;
            b_dst[i] = s * 16;
        }
    }

    f32x4 acc[2][4] = {};

    auto stage = [&](int p, int k0) {
#pragma unroll
        for (int i = 0; i < 4; i++) {
            async16(a_src[i] + k0, sA[p] + a_dst[i]);
            async16(b_src[i] + k0, sB[p] + b_dst[i]);
        }
    };

    stage(0, 0);
    __syncthreads();
    for (int it = 0; it < 32; it++) {          // BK = 64 elems (128B)
        const int p = it & 1;
        if (it + 1 < 32) stage(1 - p, (it + 1) * 64);
#pragma unroll
        for (int kk = 0; kk < 2; kk++) {       // two K=32 MFMA phases
            bf16x8 ah[2], al[2], bv[4];
#pragma unroll
            for (int i = 0; i < 2; i++) {
                const int r = (wm << 5) + (i << 4) + l16;
                const int cs = ((kk << 2) + quad) ^ (r & 7);
                ah[i] = ld_bf16_frag(sA[p] + ((r << 4) + cs) * 16);
                al[i] = ld_bf16_frag(sA[p] + ((r << 4) + 8 + cs) * 16);
            }
#pragma unroll
            for (int j = 0; j < 4; j++) {
                const int r = (wn << 6) + (j << 4) + l16;
                const int cs = ((kk << 2) + quad) ^ (r & 7);
                bv[j] = ld_bf16_frag(sB[p] + ((r << 3) + cs) * 16);
            }
#pragma unroll
            for (int i = 0; i < 2; i++)
#pragma unroll
                for (int j = 0; j < 4; j++) {
                    acc[i][j] = __builtin_amdgcn_mfma_f32_16x16x32_bf16(ah[i], bv[j], acc[i][j], 0, 0, 0);
                    acc[i][j] = __builtin_amdgcn_mfma_f32_16x16x32_bf16(al[i], bv[j], acc[i][j], 0, 0, 0);
                }
        }
        __syncthreads();
    }

#pragma unroll
    for (int i = 0; i < 2; i++) {
        const int rb = row0 + (wm << 5) + (i << 4) + (quad << 2);
#pragma unroll
        for (int j = 0; j < 4; j++) {
            const int c = col0 + (wn << 6) + (j << 4) + l16;
#pragma unroll
            for (int g = 0; g < 4; g++) {
                const size_t idx = (size_t)(rb + g) * DIM + c;
                if (MODE == 0) Cout[idx] = acc[i][j][g];
                else           Cout[idx] = Cin[idx] + acc[i][j][g] + bias[c];
            }
        }
    }
}

// ---------------- i8 recurrence step v4: A direct global->VGPR ----------------
// Round-0 geometry and sync (64x128 tile, 4 waves 32x64, 2 blocks/CU, dbuf B,
// __syncthreads drain per K-iter) -- but A (the state) skips LDS entirely:
// each lane loads its MFMA A-fragments straight from global into registers,
// one iteration ahead.  This removes A's LDS write (32KB/CU/iter) AND its
// LDS read (64KB/CU/iter), cutting the dominant LDS pipe ~2x.
// A-frag mapping (derived from the proven LDS read addressing): lane (quad,
// l16) of wave (wm,wn), sub-tile i, phase kk, plane {h,l} reads 16B at
//   row = row0 + wm*32 + i*16 + l16 ,  kbyte = it*128 + kk*64 + quad*16.
// The 4 quads of 16 rows consume whole 64B lines; the wn-wave-pair rereads
// the same lines (L1 hits).  The existing __syncthreads (vmcnt0 drain)
// certifies the prefetched regs -- no new sync semantics.
__global__ __launch_bounds__(256, 2) void step_i8(
    const signed char* __restrict__ Ah,
    const signed char* __restrict__ Al,
    const signed char* __restrict__ BT,
    const float* __restrict__ drive,
    float* __restrict__ out,
    signed char* __restrict__ Oh,
    signed char* __restrict__ Ol,
    int write_f32) {
    __shared__ alignas(16) char sB[2][16384];  // 128 rows x 128B, swizzled

    const int bid = blockIdx.x;
    const int xcd = bid & 7, slot = bid >> 3;
    const int tm = ((xcd >> 1) << 3) + (slot >> 3);      // 0..31
    const int tn = ((xcd & 1) << 3) + (slot & 7);        // 0..15
    const int row0 = tm << 6, col0 = tn << 7;

    const int tid = threadIdx.x;
    const int lane = tid & 63;
    const int quad = lane >> 4, l16 = lane & 15;
    const int wave = tid >> 6;
    const int wm = wave >> 1, wn = wave & 1;

    // B staging (identical to round-0): 4 x 16B async16/thread per buffer
    const signed char* b_src[4]; int b_dst[4];
#pragma unroll
    for (int i = 0; i < 4; i++) {
        int s = tid + 256 * i;                 // 0..1023 = 128 rows x 8 chunks
        int r = s >> 3, c = (s & 7) ^ (r & 7);
        b_src[i] = BT + (size_t)(col0 + r) * DIM + c * 16;
        b_dst[i] = s * 16;
    }

    // A-frag base: this lane's row for sub-tile i=0, k-slice quad
    const size_t a_base = (size_t)(row0 + (wm << 5) + l16) * DIM + (quad << 4);

    i32x4 acch[2][4] = {};
    i32x4 accl[2][4] = {};

    auto stageB = [&](int p, int k0) {
#pragma unroll
        for (int i = 0; i < 4; i++) async16(b_src[i] + k0, sB[p] + b_dst[i]);
    };

    // dst[i*4 + kk*2 + plane]: 8 x 16B = 32 VGPRs per set
    auto loadA = [&](i32x4* dst, int k0) {
#pragma unroll
        for (int i = 0; i < 2; i++)
#pragma unroll
            for (int kk = 0; kk < 2; kk++) {
                const size_t o = a_base + (size_t)(i << 4) * DIM + k0 + (kk << 6);
                dst[(i << 2) + (kk << 1) + 0] = *(const i32x4*)(Ah + o);
                dst[(i << 2) + (kk << 1) + 1] = *(const i32x4*)(Al + o);
            }
    };

    auto compute = [&](const char* pb, const i32x4* a) {
#pragma unroll
        for (int kk = 0; kk < 2; kk++) {       // two K=64 MFMA phases
            i32x4 bvf[4];
#pragma unroll
            for (int j = 0; j < 4; j++) {
                const int r = (wn << 6) + (j << 4) + l16;
                const int cs = ((kk << 2) + quad) ^ (r & 7);
                bvf[j] = *(const i32x4*)(pb + ((r << 3) + cs) * 16);
            }
#pragma unroll
            for (int i = 0; i < 2; i++)
#pragma unroll
                for (int j = 0; j < 4; j++) {
                    acch[i][j] = __builtin_amdgcn_mfma_i32_16x16x64_i8(a[(i << 2) + (kk << 1) + 0], bvf[j], acch[i][j], 0, 0, 0);
                    accl[i][j] = __builtin_amdgcn_mfma_i32_16x16x64_i8(a[(i << 2) + (kk << 1) + 1], bvf[j], accl[i][j], 0, 0, 0);
                }
        }
    };

    i32x4 aA[8], aB[8];   // named double-buffer (static indexing, rule #20)

    // prologue: A-frags(iter0) + B buffer 0
    loadA(aA, 0);
    stageB(0, 0);
    __syncthreads();

#pragma unroll 1
    for (int it2 = 0; it2 < 8; ++it2) {        // 16 K-iters, unrolled by 2
        const int it = it2 << 1;
        // even iter: consume sB[0] + aA, prefetch (it+1) into sB[1] + aB
        if (it + 1 < 16) { stageB(1, (it + 1) << 7); loadA(aB, (it + 1) << 7); }
        compute(sB[0], aA);
        __syncthreads();                       // drains stage(it+1) + aB loads
        // odd iter: consume sB[1] + aB, prefetch (it+2) into sB[0] + aA
        if (it + 2 < 16) { stageB(0, (it + 2) << 7); loadA(aA, (it + 2) << 7); }
        compute(sB[1], aB);
        __syncthreads();                       // drains stage(it+2) + aA loads
    }

    // epilogue: identical to proven round-0 kernel
#pragma unroll
    for (int i = 0; i < 2; i++) {
        const int rb = row0 + (wm << 5) + (i << 4) + (quad << 2);
#pragma unroll
        for (int j = 0; j < 4; j++) {
            const int c = col0 + (wn << 6) + (j << 4) + l16;
#pragma unroll
            for (int g = 0; g < 4; g++) {
                const size_t idx = (size_t)(rb + g) * DIM + c;
                int prod = acch[i][j][g] * 128 + accl[i][j][g];   // exact int
                float y = drive[idx] + (float)prod * (1.0f / 16384.0f);
                float sold = (float)((int)Ah[idx] * 128 + (int)Al[idx]) * (1.0f / 16384.0f);
                float e = __expf(2.0f * y);
                float th = 1.0f - 2.0f / (e + 1.0f);
                float s = (1.0f - LEAK) * sold + LEAK * th;
                if (write_f32) out[idx] = s;
                int q = (int)rintf(s * 16384.f);
                q = q > 16383 ? 16383 : (q < -16383 ? -16383 : q);
                Oh[idx] = (signed char)(q >> 7);
                Ol[idx] = (signed char)(q & 127);
            }
        }
    }
}

extern "C" void kernel_launch(void* const* d_in, const int* in_sizes, int n_in,
                              void* d_out, int out_size, void* d_ws, size_t ws_size,
                              hipStream_t stream) {
    const float* x    = (const float*)d_in[0];
    const float* wgt  = (const float*)d_in[1];
    const float* adj  = (const float*)d_in[2];
    const float* bias = (const float*)d_in[3];
    const float* st0  = (const float*)d_in[4];
    float* out = (float*)d_out;

    const size_t NE = (size_t)DIM * DIM;
    // ws (52 MB): adjT_i8(4) | drive(16) | bufA..bufD bf16(32);
    // i8 state ping-pong (4x4MB) aliases bufA/bufB after drive GEMMs retire.
    signed char* adjT = (signed char*)d_ws;
    float* drive = (float*)(adjT + NE);
    unsigned short* bufA = (unsigned short*)(drive + NE);
    unsigned short* bufB = bufA + NE;
    unsigned short* bufC = bufB + NE;
    unsigned short* bufD = bufC + NE;
    signed char* h1 = (signed char*)bufA;
    signed char* l1 = h1 + NE;
    signed char* h2 = l1 + NE;
    signed char* l2 = h2 + NE;

    dim3 blk(256);
    transpose_split<<<dim3(64, 64), blk, 0, stream>>>(wgt, bufC, bufD);
    split_kernel<<<dim3(4096), blk, 0, stream>>>(x, bufA, bufB);
    transpose_i8<<<dim3(64, 64), blk, 0, stream>>>(adj, adjT);

    gemm_bf16<0><<<dim3(512), blk, 0, stream>>>(bufA, bufB, bufC, (const float*)0,
                                                (const float*)0, drive);
    gemm_bf16<1><<<dim3(512), blk, 0, stream>>>(bufA, bufB, bufD, drive, bias, drive);

    quant_split<<<dim3(4096), blk, 0, stream>>>(st0, h1, l1);

    signed char* hi = h1; signed char* li = l1;
    signed char* ho = h2; signed char* lo = l2;
    for (int t = 0; t < 64; t++) {
        step_i8<<<dim3(512), blk, 0, stream>>>(hi, li, adjT, drive, out,
                                               ho, lo, (t == 63) ? 1 : 0);
        signed char* th = hi; hi = ho; ho = th;
        signed char* tl = li; li = lo; lo = tl;
    }
}

// Round 5
// 2599.213 us; speedup vs baseline: 1.2153x; 1.2153x over previous
//
#include <hip/hip_runtime.h>

#define DIM 2048
#define LEAK 0.2f

typedef __bf16 bf16x8 __attribute__((ext_vector_type(8)));
typedef float  f32x4  __attribute__((ext_vector_type(4)));
typedef unsigned int u32x4 __attribute__((ext_vector_type(4)));
typedef int    i32x4  __attribute__((ext_vector_type(4)));

static __device__ __forceinline__ unsigned short f2bf(float f) {
    unsigned int x = __float_as_uint(f);
    return (unsigned short)((x + 0x7fffu + ((x >> 16) & 1u)) >> 16);  // RNE
}
static __device__ __forceinline__ float bf2f(unsigned short h) {
    return __uint_as_float(((unsigned int)h) << 16);
}

static __device__ __forceinline__ void async16(const void* g, void* s) {
    __builtin_amdgcn_global_load_lds(
        (const __attribute__((address_space(1))) void*)g,
        (__attribute__((address_space(3))) void*)s, 16, 0, 0);
}

static __device__ __forceinline__ bf16x8 ld_bf16_frag(const char* p) {
    union { u32x4 u; bf16x8 v; } cv;
    cv.u = *(const u32x4*)p;   // ds_read_b128
    return cv.v;
}

// ---------------- prep kernels ----------------

__global__ __launch_bounds__(256) void split_kernel(
    const float* __restrict__ in,
    unsigned short* __restrict__ hi, unsigned short* __restrict__ lo) {
    int idx = blockIdx.x * 256 + threadIdx.x;
    float4 v = ((const float4*)in)[idx];
    ushort4 h, l;
    h.x = f2bf(v.x); l.x = f2bf(v.x - bf2f(h.x));
    h.y = f2bf(v.y); l.y = f2bf(v.y - bf2f(h.y));
    h.z = f2bf(v.z); l.z = f2bf(v.z - bf2f(h.z));
    h.w = f2bf(v.w); l.w = f2bf(v.w - bf2f(h.w));
    ((ushort4*)hi)[idx] = h;
    ((ushort4*)lo)[idx] = l;
}

__global__ __launch_bounds__(256) void transpose_split(
    const float* __restrict__ in,
    unsigned short* __restrict__ hiT, unsigned short* __restrict__ loT) {
    __shared__ float t[32][33];
    int bx = blockIdx.x, by = blockIdx.y;
    int tx = threadIdx.x & 31, ty4 = (threadIdx.x >> 5) << 2;
#pragma unroll
    for (int i = 0; i < 4; i++)
        t[ty4 + i][tx] = in[(size_t)(by * 32 + ty4 + i) * DIM + bx * 32 + tx];
    __syncthreads();
#pragma unroll
    for (int i = 0; i < 4; i++) {
        float v = t[tx][ty4 + i];
        size_t o = (size_t)(bx * 32 + ty4 + i) * DIM + by * 32 + tx;
        unsigned short h = f2bf(v);
        hiT[o] = h;
        loT[o] = f2bf(v - bf2f(h));
    }
}

__global__ __launch_bounds__(256) void transpose_i8(
    const float* __restrict__ in, signed char* __restrict__ outT) {
    __shared__ float t[32][33];
    int bx = blockIdx.x, by = blockIdx.y;
    int tx = threadIdx.x & 31, ty4 = (threadIdx.x >> 5) << 2;
#pragma unroll
    for (int i = 0; i < 4; i++)
        t[ty4 + i][tx] = in[(size_t)(by * 32 + ty4 + i) * DIM + bx * 32 + tx];
    __syncthreads();
#pragma unroll
    for (int i = 0; i < 4; i++)
        outT[(size_t)(bx * 32 + ty4 + i) * DIM + by * 32 + tx] =
            (signed char)t[tx][ty4 + i];
}

__global__ __launch_bounds__(256) void quant_split(
    const float* __restrict__ in,
    signed char* __restrict__ hi, signed char* __restrict__ lo) {
    int idx = blockIdx.x * 256 + threadIdx.x;
    float4 v = ((const float4*)in)[idx];
    char4 h, l;
    {
        int q = (int)rintf(v.x * 16384.f); q = q > 16383 ? 16383 : (q < -16383 ? -16383 : q);
        h.x = (signed char)(q >> 7); l.x = (signed char)(q & 127);
    }
    {
        int q = (int)rintf(v.y * 16384.f); q = q > 16383 ? 16383 : (q < -16383 ? -16383 : q);
        h.y = (signed char)(q >> 7); l.y = (signed char)(q & 127);
    }
    {
        int q = (int)rintf(v.z * 16384.f); q = q > 16383 ? 16383 : (q < -16383 ? -16383 : q);
        h.z = (signed char)(q >> 7); l.z = (signed char)(q & 127);
    }
    {
        int q = (int)rintf(v.w * 16384.f); q = q > 16383 ? 16383 : (q < -16383 ? -16383 : q);
        h.w = (signed char)(q >> 7); l.w = (signed char)(q & 127);
    }
    ((char4*)hi)[idx] = h;
    ((char4*)lo)[idx] = l;
}

// ---------------- fused bf16 dual-A/dual-B GEMM (drive) ----------------
// drive = (Ahi+Alo) @ (whi+wlo)^T + bias, in ONE kernel: the K-loop runs
// 64 iters -- first 32 over whiT, next 32 over wloT (contiguous, +NE) --
// accumulating in the same f32 regs.  Saves the 32 MB drive round-trip and
// one launch vs the previous two-pass version; per-iter structure is the
// proven round-0 schedule, byte-identical.
__global__ __launch_bounds__(256) void gemm_drive(
    const unsigned short* __restrict__ Ahi,
    const unsigned short* __restrict__ Alo,
    const unsigned short* __restrict__ BT,     // [whiT | wloT], NE apart
    const float* __restrict__ bias,
    float* __restrict__ Cout) {
    __shared__ alignas(16) char sA[2][16384];
    __shared__ alignas(16) char sB[2][16384];

    const int bid = blockIdx.x;
    const int xcd = bid & 7, slot = bid >> 3;
    const int tm = ((xcd >> 1) << 3) + (slot >> 3);      // 0..31
    const int tn = ((xcd & 1) << 3) + (slot & 7);        // 0..15
    const int row0 = tm << 6, col0 = tn << 7;

    const int tid = threadIdx.x;
    const int lane = tid & 63;
    const int quad = lane >> 4, l16 = lane & 15;
    const int wave = tid >> 6;
    const int wm = wave >> 1, wn = wave & 1;

    const unsigned short* a_src[4]; int a_dst[4];
    const unsigned short* b_src[4]; int b_dst[4];
#pragma unroll
    for (int i = 0; i < 4; i++) {
        int s = tid + 256 * i;                 // 0..1023
        {
            int r = s >> 4, g = (s >> 3) & 1, c = (s & 7) ^ (r & 7);
            a_src[i] = (g ? Alo : Ahi) + (size_t)(row0 + r) * DIM + c * 8;
            a_dst[i] = s * 16;
        }
        {
            int r = s >> 3, c = (s & 7) ^ (r & 7);
            b_src[i] = BT + (size_t)(col0 + r) * DIM + c * 8;
            b_dst[i] = s * 16;
        }
    }

    f32x4 acc[2][4] = {};

    auto stage = [&](int p, int it) {
        const int k0 = (it & 31) * 64;
        const size_t bofs = (size_t)(it >> 5) * (size_t)DIM * DIM;
#pragma unroll
        for (int i = 0; i < 4; i++) {
            async16(a_src[i] + k0, sA[p] + a_dst[i]);
            async16(b_src[i] + bofs + k0, sB[p] + b_dst[i]);
        }
    };

    stage(0, 0);
    __syncthreads();
    for (int it = 0; it < 64; it++) {          // BK = 64 elems (128B), 2 B-planes
        const int p = it & 1;
        if (it + 1 < 64) stage(1 - p, it + 1);
#pragma unroll
        for (int kk = 0; kk < 2; kk++) {       // two K=32 MFMA phases
            bf16x8 ah[2], al[2], bv[4];
#pragma unroll
            for (int i = 0; i < 2; i++) {
                const int r = (wm << 5) + (i << 4) + l16;
                const int cs = ((kk << 2) + quad) ^ (r & 7);
                ah[i] = ld_bf16_frag(sA[p] + ((r << 4) + cs) * 16);
                al[i] = ld_bf16_frag(sA[p] + ((r << 4) + 8 + cs) * 16);
            }
#pragma unroll
            for (int j = 0; j < 4; j++) {
                const int r = (wn << 6) + (j << 4) + l16;
                const int cs = ((kk << 2) + quad) ^ (r & 7);
                bv[j] = ld_bf16_frag(sB[p] + ((r << 3) + cs) * 16);
            }
#pragma unroll
            for (int i = 0; i < 2; i++)
#pragma unroll
                for (int j = 0; j < 4; j++) {
                    acc[i][j] = __builtin_amdgcn_mfma_f32_16x16x32_bf16(ah[i], bv[j], acc[i][j], 0, 0, 0);
                    acc[i][j] = __builtin_amdgcn_mfma_f32_16x16x32_bf16(al[i], bv[j], acc[i][j], 0, 0, 0);
                }
        }
        __syncthreads();
    }

#pragma unroll
    for (int i = 0; i < 2; i++) {
        const int rb = row0 + (wm << 5) + (i << 4) + (quad << 2);
#pragma unroll
        for (int j = 0; j < 4; j++) {
            const int c = col0 + (wn << 6) + (j << 4) + l16;
#pragma unroll
            for (int g = 0; g < 4; g++)
                Cout[(size_t)(rb + g) * DIM + c] = acc[i][j][g] + bias[c];
        }
    }
}

// ---------------- i8 recurrence step v5: wave-private LDS, ZERO barriers ----
// Same output mapping as round-0 (64x128 block tile, 4 waves of 32x64, grid
// 512 = 2 blocks/CU), but each wave stages its OWN 32 A-rows + 64 B-cols into
// a private 2x8KB LDS double-buffer.  No cross-wave sharing -> no
// __syncthreads in the K-loop at all; the only sync is the wave's own counted
// `s_waitcnt vmcnt(8)` (batch for iter it, issued at iter it-1, certified at
// the top of it; the 8 newest loads -- batch it+1 -- stay in flight).  The 8
// independent waves/CU sit in different phases, overlapping MFMA, LDS, and L2
// staging instead of convoying on a block barrier (the measured r0..r2 stall).
// Cost: A/B staged per-wave (2x L2 staging traffic) -- the bet is that
// removing the convoy is worth more than the extra (cheap, L2-hit) traffic.
// LDS layout per wave-buffer: A = 32 rows x 128B (8 chunks: hi 0-3 | lo 4-7,
// slot = chunk ^ (r&7)); B = 64 rows x 64B (4 chunks, slot = chunk^((r>>1)&3)).
// Both give even 8-accesses/bank for ds_read_b128 (throughput-free).
__global__ __launch_bounds__(256, 2) void step_i8(
    const signed char* __restrict__ Ah,
    const signed char* __restrict__ Al,
    const signed char* __restrict__ BT,
    const float* __restrict__ drive,
    float* __restrict__ out,
    signed char* __restrict__ Oh,
    signed char* __restrict__ Ol,
    int write_f32) {
    __shared__ alignas(16) char sW[4][2][8192];  // [wave][buf][A 0..4095 | B 4096..8191]

    const int bid = blockIdx.x;
    const int xcd = bid & 7, slot = bid >> 3;
    const int tm = ((xcd >> 1) << 3) + (slot >> 3);      // 0..31
    const int tn = ((xcd & 1) << 3) + (slot & 7);        // 0..15
    const int row0 = tm << 6, col0 = tn << 7;

    const int tid = threadIdx.x;
    const int lane = tid & 63;
    const int quad = lane >> 4, l16 = lane & 15;
    const int wave = tid >> 6;
    const int wm = wave >> 1, wn = wave & 1;
    const int wrow0 = row0 + (wm << 5);      // this wave's 32 A-rows
    const int wcol0 = col0 + (wn << 6);      // this wave's 64 B-cols

    char* const base = &sW[wave][0][0];

    // staging: 8 x 16B async16 per lane per iter (4 A + 4 B), wave-private dst
    const signed char* a_src[4]; int a_dst[4];
    const signed char* b_src[4]; int b_dst[4];
#pragma unroll
    for (int i = 0; i < 4; i++) {
        int s = (i << 6) + lane;               // 0..255
        {   // A: r = s>>3 (32 rows), slot sl = s&7, content chunk c = sl^(r&7)
            int r = s >> 3, sl = s & 7, c = sl ^ (r & 7);
            a_src[i] = ((c >> 2) ? Al : Ah) + (size_t)(wrow0 + r) * DIM + ((c & 3) << 4);
            a_dst[i] = s << 4;                 // 0..4095
        }
        {   // B: r = s>>2 (64 rows), slot sl = s&3, chunk c = sl^((r>>1)&3)
            int r = s >> 2, sl = s & 3, c = sl ^ ((r >> 1) & 3);
            b_src[i] = BT + (size_t)(wcol0 + r) * DIM + (c << 4);
            b_dst[i] = 4096 + (s << 4);
        }
    }

    // per-lane constant LDS read offsets (within a buffer)
    int aoff[2], boff[4];
#pragma unroll
    for (int i = 0; i < 2; i++) {
        int r = (i << 4) + l16;                // local A-row 0..31
        aoff[i] = (r << 7) + ((quad ^ (r & 7)) << 4);
    }
#pragma unroll
    for (int j = 0; j < 4; j++) {
        int r = (j << 4) + l16;                // local B-row 0..63
        boff[j] = 4096 + (r << 6) + ((quad ^ ((r >> 1) & 3)) << 4);
    }

    i32x4 acch[2][4] = {};
    i32x4 accl[2][4] = {};

    auto stage = [&](int p, int k0) {
        char* d = base + (p << 13);
#pragma unroll
        for (int i = 0; i < 4; i++) async16(a_src[i] + k0, d + a_dst[i]);
#pragma unroll
        for (int i = 0; i < 4; i++) async16(b_src[i] + k0, d + b_dst[i]);
    };

    auto compute = [&](const char* pw) {
        i32x4 ah[2], al[2], bv[4];
#pragma unroll
        for (int i = 0; i < 2; i++) {
            ah[i] = *(const i32x4*)(pw + aoff[i]);
            al[i] = *(const i32x4*)(pw + (aoff[i] ^ 64));   // lo slot = hi slot ^ 4
        }
#pragma unroll
        for (int j = 0; j < 4; j++) bv[j] = *(const i32x4*)(pw + boff[j]);
        __builtin_amdgcn_s_setprio(1);
#pragma unroll
        for (int i = 0; i < 2; i++)
#pragma unroll
            for (int j = 0; j < 4; j++) {
                acch[i][j] = __builtin_amdgcn_mfma_i32_16x16x64_i8(ah[i], bv[j], acch[i][j], 0, 0, 0);
                accl[i][j] = __builtin_amdgcn_mfma_i32_16x16x64_i8(al[i], bv[j], accl[i][j], 0, 0, 0);
            }
        __builtin_amdgcn_s_setprio(0);
    };

    stage(0, 0);                                // batch for iter 0
#pragma unroll 2
    for (int it = 0; it < 32; ++it) {           // BK = 64 bytes of k
        const int p = it & 1;
        if (it + 1 < 32) {
            stage(1 - p, (it + 1) << 6);        // batch(it+1): 8 newest in flight
            __builtin_amdgcn_sched_barrier(0);
            asm volatile("s_waitcnt vmcnt(8)" ::: "memory");   // batch(it) landed
        } else {
            asm volatile("s_waitcnt vmcnt(0)" ::: "memory");
        }
        compute(base + (p << 13));
    }

    // epilogue: identical math to proven round-0 kernel
#pragma unroll
    for (int i = 0; i < 2; i++) {
        const int rb = wrow0 + (i << 4) + (quad << 2);
#pragma unroll
        for (int j = 0; j < 4; j++) {
            const int c = wcol0 + (j << 4) + l16;
#pragma unroll
            for (int g = 0; g < 4; g++) {
                const size_t idx = (size_t)(rb + g) * DIM + c;
                int prod = acch[i][j][g] * 128 + accl[i][j][g];   // exact int
                float y = drive[idx] + (float)prod * (1.0f / 16384.0f);
                float sold = (float)((int)Ah[idx] * 128 + (int)Al[idx]) * (1.0f / 16384.0f);
                float e = __expf(2.0f * y);
                float th = 1.0f - 2.0f / (e + 1.0f);
                float s = (1.0f - LEAK) * sold + LEAK * th;
                if (write_f32) out[idx] = s;
                int q = (int)rintf(s * 16384.f);
                q = q > 16383 ? 16383 : (q < -16383 ? -16383 : q);
                Oh[idx] = (signed char)(q >> 7);
                Ol[idx] = (signed char)(q & 127);
            }
        }
    }
}

extern "C" void kernel_launch(void* const* d_in, const int* in_sizes, int n_in,
                              void* d_out, int out_size, void* d_ws, size_t ws_size,
                              hipStream_t stream) {
    const float* x    = (const float*)d_in[0];
    const float* wgt  = (const float*)d_in[1];
    const float* adj  = (const float*)d_in[2];
    const float* bias = (const float*)d_in[3];
    const float* st0  = (const float*)d_in[4];
    float* out = (float*)d_out;

    const size_t NE = (size_t)DIM * DIM;
    // ws (52 MB): adjT_i8(4) | drive(16) | bufA..bufD bf16(32);
    // i8 state ping-pong (4x4MB) aliases bufA/bufB after drive GEMM retires.
    signed char* adjT = (signed char*)d_ws;
    float* drive = (float*)(adjT + NE);
    unsigned short* bufA = (unsigned short*)(drive + NE);
    unsigned short* bufB = bufA + NE;
    unsigned short* bufC = bufB + NE;   // whiT
    unsigned short* bufD = bufC + NE;   // wloT (contiguous after whiT)
    signed char* h1 = (signed char*)bufA;
    signed char* l1 = h1 + NE;
    signed char* h2 = l1 + NE;
    signed char* l2 = h2 + NE;

    dim3 blk(256);
    transpose_split<<<dim3(64, 64), blk, 0, stream>>>(wgt, bufC, bufD);
    split_kernel<<<dim3(4096), blk, 0, stream>>>(x, bufA, bufB);
    transpose_i8<<<dim3(64, 64), blk, 0, stream>>>(adj, adjT);

    gemm_drive<<<dim3(512), blk, 0, stream>>>(bufA, bufB, bufC, bias, drive);

    quant_split<<<dim3(4096), blk, 0, stream>>>(st0, h1, l1);

    signed char* hi = h1; signed char* li = l1;
    signed char* ho = h2; signed char* lo = l2;
    for (int t = 0; t < 64; t++) {
        step_i8<<<dim3(512), blk, 0, stream>>>(hi, li, adjT, drive, out,
                                               ho, lo, (t == 63) ? 1 : 0);
        signed char* th = hi; hi = ho; ho = th;
        signed char* tl = li; li = lo; lo = tl;
    }
}

// Round 6
// 2525.222 us; speedup vs baseline: 1.2509x; 1.0293x over previous
//
#include <hip/hip_runtime.h>

#define DIM 2048
#define LEAK 0.2f

typedef __bf16 bf16x8 __attribute__((ext_vector_type(8)));
typedef float  f32x4  __attribute__((ext_vector_type(4)));
typedef unsigned int u32x4 __attribute__((ext_vector_type(4)));
typedef int    i32x4  __attribute__((ext_vector_type(4)));

static __device__ __forceinline__ unsigned short f2bf(float f) {
    unsigned int x = __float_as_uint(f);
    return (unsigned short)((x + 0x7fffu + ((x >> 16) & 1u)) >> 16);  // RNE
}
static __device__ __forceinline__ float bf2f(unsigned short h) {
    return __uint_as_float(((unsigned int)h) << 16);
}

static __device__ __forceinline__ void async16(const void* g, void* s) {
    __builtin_amdgcn_global_load_lds(
        (const __attribute__((address_space(1))) void*)g,
        (__attribute__((address_space(3))) void*)s, 16, 0, 0);
}

static __device__ __forceinline__ bf16x8 ld_bf16_frag(const char* p) {
    union { u32x4 u; bf16x8 v; } cv;
    cv.u = *(const u32x4*)p;   // ds_read_b128
    return cv.v;
}

// ---------------- prep kernels ----------------

__global__ __launch_bounds__(256) void split_kernel(
    const float* __restrict__ in,
    unsigned short* __restrict__ hi, unsigned short* __restrict__ lo) {
    int idx = blockIdx.x * 256 + threadIdx.x;
    float4 v = ((const float4*)in)[idx];
    ushort4 h, l;
    h.x = f2bf(v.x); l.x = f2bf(v.x - bf2f(h.x));
    h.y = f2bf(v.y); l.y = f2bf(v.y - bf2f(h.y));
    h.z = f2bf(v.z); l.z = f2bf(v.z - bf2f(h.z));
    h.w = f2bf(v.w); l.w = f2bf(v.w - bf2f(h.w));
    ((ushort4*)hi)[idx] = h;
    ((ushort4*)lo)[idx] = l;
}

__global__ __launch_bounds__(256) void transpose_split(
    const float* __restrict__ in,
    unsigned short* __restrict__ hiT, unsigned short* __restrict__ loT) {
    __shared__ float t[32][33];
    int bx = blockIdx.x, by = blockIdx.y;
    int tx = threadIdx.x & 31, ty4 = (threadIdx.x >> 5) << 2;
#pragma unroll
    for (int i = 0; i < 4; i++)
        t[ty4 + i][tx] = in[(size_t)(by * 32 + ty4 + i) * DIM + bx * 32 + tx];
    __syncthreads();
#pragma unroll
    for (int i = 0; i < 4; i++) {
        float v = t[tx][ty4 + i];
        size_t o = (size_t)(bx * 32 + ty4 + i) * DIM + by * 32 + tx;
        unsigned short h = f2bf(v);
        hiT[o] = h;
        loT[o] = f2bf(v - bf2f(h));
    }
}

__global__ __launch_bounds__(256) void transpose_i8(
    const float* __restrict__ in, signed char* __restrict__ outT) {
    __shared__ float t[32][33];
    int bx = blockIdx.x, by = blockIdx.y;
    int tx = threadIdx.x & 31, ty4 = (threadIdx.x >> 5) << 2;
#pragma unroll
    for (int i = 0; i < 4; i++)
        t[ty4 + i][tx] = in[(size_t)(by * 32 + ty4 + i) * DIM + bx * 32 + tx];
    __syncthreads();
#pragma unroll
    for (int i = 0; i < 4; i++)
        outT[(size_t)(bx * 32 + ty4 + i) * DIM + by * 32 + tx] =
            (signed char)t[tx][ty4 + i];
}

__global__ __launch_bounds__(256) void quant_split(
    const float* __restrict__ in,
    signed char* __restrict__ hi, signed char* __restrict__ lo) {
    int idx = blockIdx.x * 256 + threadIdx.x;
    float4 v = ((const float4*)in)[idx];
    char4 h, l;
    {
        int q = (int)rintf(v.x * 16384.f); q = q > 16383 ? 16383 : (q < -16383 ? -16383 : q);
        h.x = (signed char)(q >> 7); l.x = (signed char)(q & 127);
    }
    {
        int q = (int)rintf(v.y * 16384.f); q = q > 16383 ? 16383 : (q < -16383 ? -16383 : q);
        h.y = (signed char)(q >> 7); l.y = (signed char)(q & 127);
    }
    {
        int q = (int)rintf(v.z * 16384.f); q = q > 16383 ? 16383 : (q < -16383 ? -16383 : q);
        h.z = (signed char)(q >> 7); l.z = (signed char)(q & 127);
    }
    {
        int q = (int)rintf(v.w * 16384.f); q = q > 16383 ? 16383 : (q < -16383 ? -16383 : q);
        h.w = (signed char)(q >> 7); l.w = (signed char)(q & 127);
    }
    ((char4*)hi)[idx] = h;
    ((char4*)lo)[idx] = l;
}

// ---------------- bf16 dual-A GEMM (drive), tile 64x128, dbuf ----------------
// MODE 0: Cout = (Ahi+Alo) @ B^T        MODE 1: Cout = Cin + P + bias[n]
// (proven round-0 kernel, 2x44us -- fused variant measured slower, reverted)
template <int MODE>
__global__ __launch_bounds__(256) void gemm_bf16(
    const unsigned short* __restrict__ Ahi,
    const unsigned short* __restrict__ Alo,
    const unsigned short* __restrict__ BT,
    const float* __restrict__ Cin,
    const float* __restrict__ bias,
    float* __restrict__ Cout) {
    __shared__ alignas(16) char sA[2][16384];
    __shared__ alignas(16) char sB[2][16384];

    const int bid = blockIdx.x;
    const int xcd = bid & 7, slot = bid >> 3;
    const int tm = ((xcd >> 1) << 3) + (slot >> 3);      // 0..31
    const int tn = ((xcd & 1) << 3) + (slot & 7);        // 0..15
    const int row0 = tm << 6, col0 = tn << 7;

    const int tid = threadIdx.x;
    const int lane = tid & 63;
    const int quad = lane >> 4, l16 = lane & 15;
    const int wave = tid >> 6;
    const int wm = wave >> 1, wn = wave & 1;

    const unsigned short* a_src[4]; int a_dst[4];
    const unsigned short* b_src[4]; int b_dst[4];
#pragma unroll
    for (int i = 0; i < 4; i++) {
        int s = tid + 256 * i;                 // 0..1023
        {
            int r = s >> 4, g = (s >> 3) & 1, c = (s & 7) ^ (r & 7);
            a_src[i] = (g ? Alo : Ahi) + (size_t)(row0 + r) * DIM + c * 8;
            a_dst[i] = s * 16;
        }
        {
            int r = s >> 3, c = (s & 7) ^ (r & 7);
            b_src[i] = BT + (size_t)(col0 + r) * DIM + c * 8;
            b_dst[i] = s * 16;
        }
    }

    f32x4 acc[2][4] = {};

    auto stage = [&](int p, int k0) {
#pragma unroll
        for (int i = 0; i < 4; i++) {
            async16(a_src[i] + k0, sA[p] + a_dst[i]);
            async16(b_src[i] + k0, sB[p] + b_dst[i]);
        }
    };

    stage(0, 0);
    __syncthreads();
    for (int it = 0; it < 32; it++) {          // BK = 64 elems (128B)
        const int p = it & 1;
        if (it + 1 < 32) stage(1 - p, (it + 1) * 64);
#pragma unroll
        for (int kk = 0; kk < 2; kk++) {       // two K=32 MFMA phases
            bf16x8 ah[2], al[2], bv[4];
#pragma unroll
            for (int i = 0; i < 2; i++) {
                const int r = (wm << 5) + (i << 4) + l16;
                const int cs = ((kk << 2) + quad) ^ (r & 7);
                ah[i] = ld_bf16_frag(sA[p] + ((r << 4) + cs) * 16);
                al[i] = ld_bf16_frag(sA[p] + ((r << 4) + 8 + cs) * 16);
            }
#pragma unroll
            for (int j = 0; j < 4; j++) {
                const int r = (wn << 6) + (j << 4) + l16;
                const int cs = ((kk << 2) + quad) ^ (r & 7);
                bv[j] = ld_bf16_frag(sB[p] + ((r << 3) + cs) * 16);
            }
#pragma unroll
            for (int i = 0; i < 2; i++)
#pragma unroll
                for (int j = 0; j < 4; j++) {
                    acc[i][j] = __builtin_amdgcn_mfma_f32_16x16x32_bf16(ah[i], bv[j], acc[i][j], 0, 0, 0);
                    acc[i][j] = __builtin_amdgcn_mfma_f32_16x16x32_bf16(al[i], bv[j], acc[i][j], 0, 0, 0);
                }
        }
        __syncthreads();
    }

#pragma unroll
    for (int i = 0; i < 2; i++) {
        const int rb = row0 + (wm << 5) + (i << 4) + (quad << 2);
#pragma unroll
        for (int j = 0; j < 4; j++) {
            const int c = col0 + (wn << 6) + (j << 4) + l16;
#pragma unroll
            for (int g = 0; g < 4; g++) {
                const size_t idx = (size_t)(rb + g) * DIM + c;
                if (MODE == 0) Cout[idx] = acc[i][j][g];
                else           Cout[idx] = Cin[idx] + acc[i][j][g] + bias[c];
            }
        }
    }
}

// ---------------- i8 recurrence step v6: 64x64 tile, 2 waves, 4+ blocks/CU ----
// Wave tile stays the proven 32x64; block shrinks to 64x64 (2 waves, 128 thr)
// with BK=64B so LDS = 24KB/block -> 4 blocks/CU average (grid 1024), 6 max.
// Schedule/sync is byte-identical to round-0 (stage next, compute, syncthreads
// drain): the change is PARALLELISM -- 8 independent 2-wave convoys per CU
// instead of 2 lockstep 4-wave blocks, so when one block sits in its barrier
// drain the other blocks' waves issue MFMA/LDS/VMEM (m114 overlap).
// LDS layouts (both HW-proven in r2, minimal 8 words/bank on ds_read_b128):
//   sA: 64 rows x 128B = 8x16B chunks (hi 0-3 | lo 4-7), slot = chunk^(r&7);
//       lo read addr = hi addr ^ 64.
//   sB: 64 rows x 64B = 4 chunks, slot = chunk^((r>>1)&3).
__global__ __launch_bounds__(128, 2) void step_i8(
    const signed char* __restrict__ Ah,
    const signed char* __restrict__ Al,
    const signed char* __restrict__ BT,
    const float* __restrict__ drive,
    float* __restrict__ out,
    signed char* __restrict__ Oh,
    signed char* __restrict__ Ol,
    int write_f32) {
    __shared__ alignas(16) char sA[2][8192];   // 64 rows x 128B
    __shared__ alignas(16) char sB[2][4096];   // 64 rows x 64B

    const int bid = blockIdx.x;                // 1024 blocks
    const int xcd = bid & 7, slot = bid >> 3;  // 8 XCDs x 128 slots
    const int tm = ((xcd >> 1) << 3) + (slot >> 4);   // 0..31
    const int tn = ((xcd & 1) << 4) + (slot & 15);    // 0..31
    const int row0 = tm << 6, col0 = tn << 6;

    const int tid = threadIdx.x;               // 0..127 (2 waves)
    const int lane = tid & 63;
    const int quad = lane >> 4, l16 = lane & 15;
    const int wm = tid >> 6;                   // wave id -> 32-row half

    // staging: 6 x 16B async16 per thread per iter (4 A + 2 B)
    const signed char* a_src[4]; int a_dst[4];
    const signed char* b_src[2]; int b_dst[2];
#pragma unroll
    for (int i = 0; i < 4; i++) {
        int s = (i << 7) + tid;                // 0..511 = 64 rows x 8 chunks
        int r = s >> 3, sl = s & 7, c = sl ^ (r & 7);
        a_src[i] = ((c >> 2) ? Al : Ah) + (size_t)(row0 + r) * DIM + ((c & 3) << 4);
        a_dst[i] = s << 4;
    }
#pragma unroll
    for (int i = 0; i < 2; i++) {
        int s = (i << 7) + tid;                // 0..255 = 64 rows x 4 chunks
        int r = s >> 2, sl = s & 3, c = sl ^ ((r >> 1) & 3);
        b_src[i] = BT + (size_t)(col0 + r) * DIM + (c << 4);
        b_dst[i] = s << 4;
    }

    // per-lane constant LDS read offsets
    int aoff[2], boff[4];
#pragma unroll
    for (int i = 0; i < 2; i++) {
        int r = (wm << 5) + (i << 4) + l16;    // A row 0..63
        aoff[i] = (r << 7) + ((quad ^ (r & 7)) << 4);
    }
#pragma unroll
    for (int j = 0; j < 4; j++) {
        int r = (j << 4) + l16;                // B row (col) 0..63
        boff[j] = (r << 6) + ((quad ^ ((r >> 1) & 3)) << 4);
    }

    i32x4 acch[2][4] = {};
    i32x4 accl[2][4] = {};

    auto stage = [&](int p, int k0) {
#pragma unroll
        for (int i = 0; i < 4; i++) async16(a_src[i] + k0, sA[p] + a_dst[i]);
#pragma unroll
        for (int i = 0; i < 2; i++) async16(b_src[i] + k0, sB[p] + b_dst[i]);
    };

    stage(0, 0);
    __syncthreads();
    for (int it = 0; it < 32; it++) {          // BK = 64 bytes of k
        const int p = it & 1;
        if (it + 1 < 32) stage(1 - p, (it + 1) << 6);
        // one K=64 MFMA phase
        i32x4 ah[2], al[2], bv[4];
#pragma unroll
        for (int i = 0; i < 2; i++) {
            ah[i] = *(const i32x4*)(sA[p] + aoff[i]);
            al[i] = *(const i32x4*)(sA[p] + (aoff[i] ^ 64));
        }
#pragma unroll
        for (int j = 0; j < 4; j++) bv[j] = *(const i32x4*)(sB[p] + boff[j]);
#pragma unroll
        for (int i = 0; i < 2; i++)
#pragma unroll
            for (int j = 0; j < 4; j++) {
                acch[i][j] = __builtin_amdgcn_mfma_i32_16x16x64_i8(ah[i], bv[j], acch[i][j], 0, 0, 0);
                accl[i][j] = __builtin_amdgcn_mfma_i32_16x16x64_i8(al[i], bv[j], accl[i][j], 0, 0, 0);
            }
        __syncthreads();
    }

    // epilogue: proven round-0 math, 64-col tile
#pragma unroll
    for (int i = 0; i < 2; i++) {
        const int rb = row0 + (wm << 5) + (i << 4) + (quad << 2);
#pragma unroll
        for (int j = 0; j < 4; j++) {
            const int c = col0 + (j << 4) + l16;
#pragma unroll
            for (int g = 0; g < 4; g++) {
                const size_t idx = (size_t)(rb + g) * DIM + c;
                int prod = acch[i][j][g] * 128 + accl[i][j][g];   // exact int
                float y = drive[idx] + (float)prod * (1.0f / 16384.0f);
                float sold = (float)((int)Ah[idx] * 128 + (int)Al[idx]) * (1.0f / 16384.0f);
                float e = __expf(2.0f * y);
                float th = 1.0f - 2.0f / (e + 1.0f);
                float s = (1.0f - LEAK) * sold + LEAK * th;
                if (write_f32) out[idx] = s;
                int q = (int)rintf(s * 16384.f);
                q = q > 16383 ? 16383 : (q < -16383 ? -16383 : q);
                Oh[idx] = (signed char)(q >> 7);
                Ol[idx] = (signed char)(q & 127);
            }
        }
    }
}

extern "C" void kernel_launch(void* const* d_in, const int* in_sizes, int n_in,
                              void* d_out, int out_size, void* d_ws, size_t ws_size,
                              hipStream_t stream) {
    const float* x    = (const float*)d_in[0];
    const float* wgt  = (const float*)d_in[1];
    const float* adj  = (const float*)d_in[2];
    const float* bias = (const float*)d_in[3];
    const float* st0  = (const float*)d_in[4];
    float* out = (float*)d_out;

    const size_t NE = (size_t)DIM * DIM;
    // ws (52 MB): adjT_i8(4) | drive(16) | bufA..bufD bf16(32);
    // i8 state ping-pong (4x4MB) aliases bufA/bufB after drive GEMMs retire.
    signed char* adjT = (signed char*)d_ws;
    float* drive = (float*)(adjT + NE);
    unsigned short* bufA = (unsigned short*)(drive + NE);
    unsigned short* bufB = bufA + NE;
    unsigned short* bufC = bufB + NE;
    unsigned short* bufD = bufC + NE;
    signed char* h1 = (signed char*)bufA;
    signed char* l1 = h1 + NE;
    signed char* h2 = l1 + NE;
    signed char* l2 = h2 + NE;

    dim3 blk(256);
    transpose_split<<<dim3(64, 64), blk, 0, stream>>>(wgt, bufC, bufD);
    split_kernel<<<dim3(4096), blk, 0, stream>>>(x, bufA, bufB);
    transpose_i8<<<dim3(64, 64), blk, 0, stream>>>(adj, adjT);

    gemm_bf16<0><<<dim3(512), blk, 0, stream>>>(bufA, bufB, bufC, (const float*)0,
                                                (const float*)0, drive);
    gemm_bf16<1><<<dim3(512), blk, 0, stream>>>(bufA, bufB, bufD, drive, bias, drive);

    quant_split<<<dim3(4096), blk, 0, stream>>>(st0, h1, l1);

    signed char* hi = h1; signed char* li = l1;
    signed char* ho = h2; signed char* lo = l2;
    for (int t = 0; t < 64; t++) {
        step_i8<<<dim3(1024), dim3(128), 0, stream>>>(hi, li, adjT, drive, out,
                                                      ho, lo, (t == 63) ? 1 : 0);
        signed char* th = hi; hi = ho; ho = th;
        signed char* tl = li; li = lo; lo = tl;
    }
}